// Round 7
// baseline (184.799 us; speedup 1.0000x reference)
//
#include <hip/hip_runtime.h>
#include <hip/hip_bf16.h>

typedef __attribute__((ext_vector_type(8))) short short8;
typedef __attribute__((ext_vector_type(4))) float floatx4;

#define TL2  20.60992915555662f                  // (1/0.07)*log2(e); A pre-scaled by TL2, B raw
#define LN2  0.6931471805599453f
#define NROWS 8192
#define NDIM 128
#define NCH 16
#define NITS 16                                  // 16 x 32 cols = 512-col chunk
#define NBLOCKS 1024

__device__ __forceinline__ float fexp2(float x) {
#if __has_builtin(__builtin_amdgcn_exp2f)
    return __builtin_amdgcn_exp2f(x);
#else
    return __expf(x * LN2);
#endif
}

// ONE kernel, no cooperative launch (round-6 grid.sync failed under graph capture):
// - B-tiles staged as fp32 straight from feat via global_load_lds; bf16 cvt in regs.
//   LDS layout [h][kc][col] makes ds_read addr = l4*512 + l15*16 — the exact
//   zero-conflict pattern measured in round 4.
// - A-fragments converted once per block, scaled by TL2 (so B needs no scaling;
//   product = TL2*a*b, same two-bf16-rounding structure as the passing kernel).
// - final reduce done by the LAST block (device-scope atomic counter + threadfence
//   release/acquire): no 2nd/3rd launch, no dispatch-order assumption.
__global__ __launch_bounds__(512, 4) void fused_kernel(
    const float* __restrict__ feat,
    const int* __restrict__ labels,
    float* __restrict__ sM, float* __restrict__ sS, float* __restrict__ sP,
    unsigned int* __restrict__ ctr, float* __restrict__ nacc,
    float* __restrict__ out)
{
    __shared__ __align__(16) float stage[2][2 * 16 * 32 * 4];  // [buf][h][kc][col][4f], 16KB/buf
    __shared__ float nredW[8];
    __shared__ int lab3[512];
    __shared__ int hist3[16];
    __shared__ float red3[512];
    __shared__ int amLast;

    const int tid = threadIdx.x;
    const int bid = blockIdx.x;
    const int rb = bid & 63;
    const int q  = bid >> 6;
    const int rowBase = rb << 7;
    const int colBase = q << 9;
    const int w = __builtin_amdgcn_readfirstlane(tid >> 6);   // wave id 0..7 -> SGPR
    const int lane = tid & 63;
    const int l15 = lane & 15;
    const int l4  = lane >> 4;

// stage fp32 tile IT (32 cols x 128 dims) into buffer BUF: 2 instrs/wave, 1KB each.
// instr h: lanes 0-31 -> kc=2w col=lane, lanes 32-63 -> kc=2w+1. LDS dest is
// wave-uniform base; HW adds lane*16B -> linear [h][kc][col] layout.
#define ISSUE(IT, BUF)                                                                   \
    {                                                                                    \
        const int kcb = (w << 1);                                                        \
        float* sbase = &stage[BUF][0];                                                   \
        _Pragma("unroll")                                                                \
        for (int h = 0; h < 2; ++h) {                                                    \
            const float* src = feat +                                                    \
                (size_t)(colBase + ((IT) << 5) + (lane & 31)) * NDIM +                   \
                ((kcb + (lane >> 5)) << 3) + (h << 2);                                   \
            __builtin_amdgcn_global_load_lds(                                            \
                (const __attribute__((address_space(1))) unsigned int*)src,              \
                (__attribute__((address_space(3))) unsigned int*)                        \
                    (sbase + h * 2048 + kcb * 128),                                      \
                16, 0, 0);                                                               \
        }                                                                                \
    }

    ISSUE(0, 0)

    // A fragments: wave owns 16 rows; convert fp32 -> bf16 (xTL2) once per block
    const int rw = rowBase + w * 16;                 // SGPR
    const int brow = rw >> 4;
    const int lrow = labels[brow];                    // uniform addr -> s_load
    short8 afrag[4];
    #pragma unroll
    for (int t = 0; t < 4; ++t) {
        const float4* pa = (const float4*)(feat + (size_t)(rw + l15) * NDIM + ((t * 4 + l4) << 3));
        const float4 a = pa[0], b = pa[1];
        union { short8 s; __hip_bfloat162 h2[4]; } u;
        u.h2[0] = __float22bfloat162_rn(float2{a.x * TL2, a.y * TL2});
        u.h2[1] = __float22bfloat162_rn(float2{a.z * TL2, a.w * TL2});
        u.h2[2] = __float22bfloat162_rn(float2{b.x * TL2, b.y * TL2});
        u.h2[3] = __float22bfloat162_rn(float2{b.z * TL2, b.w * TL2});
        afrag[t] = u.s;
    }

    // scalar class-match mask over the 32 col-16 tiles of this chunk
    const int cb16 = colBase >> 4;
    unsigned pms = 0u;
    #pragma unroll
    for (int c = 0; c < 32; ++c)
        if (labels[cb16 + c] == lrow) pms |= (1u << c);

    float tm[4], su[4], ps[4];
    #pragma unroll
    for (int r = 0; r < 4; ++r) { tm[r] = -1e30f; su[r] = 0.0f; ps[r] = 0.0f; }
    float noise_acc = 0.0f;

    for (int it = 0; it < NITS; ++it) {
        __syncthreads();                 // drains my tile-it loads (vmcnt 0) + barrier
        if (it + 1 < NITS) ISSUE(it + 1, (it + 1) & 1)

        const float4* stv = (const float4*)stage[it & 1];
        floatx4 vacc[2];
        #pragma unroll
        for (int c = 0; c < 2; ++c) {
            floatx4 acc = {0.0f, 0.0f, 0.0f, 0.0f};
            #pragma unroll
            for (int t = 0; t < 4; ++t) {
                const int ui = (t * 4 + l4) * 32 + (c << 4) + l15;
                const float4 lo = stv[ui];          // dims 0-3 of this kc (conflict-free)
                const float4 hi = stv[512 + ui];    // dims 4-7
                union { short8 s; __hip_bfloat162 h2[4]; } u;
                u.h2[0] = __float22bfloat162_rn(float2{lo.x, lo.y});
                u.h2[1] = __float22bfloat162_rn(float2{lo.z, lo.w});
                u.h2[2] = __float22bfloat162_rn(float2{hi.x, hi.y});
                u.h2[3] = __float22bfloat162_rn(float2{hi.z, hi.w});
                acc = __builtin_amdgcn_mfma_f32_16x16x32_bf16(afrag[t], u.s, acc, 0, 0, 0);
            }
            vacc[c] = acc;
        }

        const int base16 = cb16 + (it << 1);
        const int nt = brow - base16;          // same-batch tile index if in [0,2) — scalar
        const bool anyn = ((unsigned)nt) < 2u; // wave-uniform scalar
        int posm = (int)((pms >> (it << 1)) & 3u);
        if (anyn) posm &= ~(1 << nt);          // drop same-batch tile from positives
        #pragma unroll
        for (int r = 0; r < 4; ++r) {
            const float v0 = vacc[0][r], v1 = vacc[1][r];
            if (!anyn) {
                const float lmax = fmaxf(v0, v1);
                const float tmr = tm[r];
                if (__any(lmax > tmr)) {
                    const float tnm = fmaxf(tmr, lmax);
                    su[r] = fmaf(su[r], fexp2(tmr - tnm),
                                 fexp2(v0 - tnm) + fexp2(v1 - tnm));
                    tm[r] = tnm;
                } else {   // steady state: no rescale
                    su[r] += fexp2(v0 - tmr) + fexp2(v1 - tmr);
                }
            } else {       // one of the two 16-tiles is same-batch (invalid + noise)
                const float vv = nt ? v0 : v1;   // the valid tile's value
                const float vn = nt ? v1 : v0;   // the same-batch tile's value
                const float tmr = tm[r];
                const float tnm = fmaxf(tmr, vv);
                su[r] = fmaf(su[r], fexp2(tmr - tnm), fexp2(vv - tnm));
                tm[r] = tnm;
                const int rl = (l4 << 2) + r;
                if ((rl >> 3) == (l15 >> 3) && rl != l15) noise_acc += vn;
            }
            if (posm & 1) ps[r] += v0;
            if (posm & 2) ps[r] += v1;
        }
    }
#undef ISSUE

    // combine the 16 lane-partials per row via shuffles (l15 groups hold one row)
    #pragma unroll
    for (int r = 0; r < 4; ++r) {
        float tmv = tm[r], suv = su[r], psv = ps[r];
        #pragma unroll
        for (int off = 1; off < 16; off <<= 1) {
            float om = __shfl_xor(tmv, off);
            float os = __shfl_xor(suv, off);
            float op = __shfl_xor(psv, off);
            float nm = fmaxf(tmv, om);
            suv = suv * fexp2(tmv - nm) + os * fexp2(om - nm);
            tmv = nm; psv += op;
        }
        if (l15 == 0) {
            int row = rw + (l4 << 2) + r;
            sM[row * NCH + q] = tmv;
            sS[row * NCH + q] = suv;
            sP[row * NCH + q] = psv;
        }
    }

    float na = noise_acc;
    #pragma unroll
    for (int off = 32; off >= 1; off >>= 1) na += __shfl_xor(na, off);
    if (lane == 0) nredW[w] = na;
    __syncthreads();   // also completes (vmcnt) all this block's sM/sS/sP stores

    // ---- completion protocol: last block does the final reduce ----
    if (tid == 0) {
        float s = 0.0f;
        #pragma unroll
        for (int j = 0; j < 8; ++j) s += nredW[j];
        atomicAdd(nacc, s);                       // device-scope (m20)
        __threadfence();                          // release: wbl2 before counter bump
        const unsigned old = atomicAdd(ctr, 1u);
        amLast = (old == NBLOCKS - 1u);
    }
    __syncthreads();
    if (!amLast) return;
    __threadfence();                              // acquire: inv L1/L2 before reading sM/sS/sP

    // ---- final phase (one block, 512 threads, 16 rows each) ----
    if (tid < 16) hist3[tid] = 0;
    lab3[tid] = labels[tid];
    __syncthreads();
    atomicAdd(&hist3[lab3[tid] & 15], 1);
    __syncthreads();

    float facc = 0.0f;
    #pragma clang loop unroll(disable)
    for (int rr = 0; rr < 16; ++rr) {             // keep body small: no unroll -> no spill
        const int row = (rr << 9) + tid;
        const float4* M4 = (const float4*)(sM + (size_t)row * NCH);
        const float4* S4 = (const float4*)(sS + (size_t)row * NCH);
        const float4* P4 = (const float4*)(sP + (size_t)row * NCH);
        float mq[NCH], sq[NCH], pq[NCH];
        #pragma unroll
        for (int j = 0; j < 4; ++j) {
            float4 a = M4[j]; mq[4*j] = a.x; mq[4*j+1] = a.y; mq[4*j+2] = a.z; mq[4*j+3] = a.w;
            float4 b = S4[j]; sq[4*j] = b.x; sq[4*j+1] = b.y; sq[4*j+2] = b.z; sq[4*j+3] = b.w;
            float4 c = P4[j]; pq[4*j] = c.x; pq[4*j+1] = c.y; pq[4*j+2] = c.z; pq[4*j+3] = c.w;
        }
        float gm = -1e30f;
        #pragma unroll
        for (int qq = 0; qq < NCH; ++qq) gm = fmaxf(gm, mq[qq]);
        float gs = 0.0f, gp = 0.0f;
        #pragma unroll
        for (int qq = 0; qq < NCH; ++qq) { gs += sq[qq] * fexp2(mq[qq] - gm); gp += pq[qq]; }
        const float P = 16.0f * (float)(hist3[lab3[row >> 4] & 15] - 1);
        facc += LN2 * (P * (gm + __log2f(gs)) - gp) / (P + 1e-8f);
    }
    red3[tid] = facc;
    __syncthreads();
    #pragma unroll
    for (int off = 256; off > 0; off >>= 1) {
        if (tid < off) red3[tid] += red3[tid + off];
        __syncthreads();
    }
    if (tid == 0) {
        const float nz = __hip_atomic_load(nacc, __ATOMIC_RELAXED, __HIP_MEMORY_SCOPE_AGENT);
        out[0] = red3[0] * (1.0f / (8192.0f * 3.0f))
               + nz * (-LN2 / (57344.0f * 0.07f * 3.0f));
    }
}

extern "C" void kernel_launch(void* const* d_in, const int* in_sizes, int n_in,
                              void* d_out, int out_size, void* d_ws, size_t ws_size,
                              hipStream_t stream) {
    const float* feat  = (const float*)d_in[0];
    const int* labels  = (const int*)d_in[1];
    float* out = (float*)d_out;

    float* wsf = (float*)d_ws;
    float* sM  = wsf;                      // 8192*16
    float* sS  = wsf + 131072;
    float* sP  = wsf + 262144;
    unsigned int* ctr = (unsigned int*)(wsf + 393216);
    float* nacc = (float*)(wsf + 393217);

    hipMemsetAsync((void*)ctr, 0, 8, stream);     // zero counter + noise accumulator
    hipLaunchKernelGGL(fused_kernel, dim3(NBLOCKS), dim3(512), 0, stream,
                       feat, labels, sM, sS, sP, ctr, nacc, out);
}

// Round 8
// 128.055 us; speedup vs baseline: 1.4431x; 1.4431x over previous
//
#include <hip/hip_runtime.h>
#include <hip/hip_bf16.h>

typedef __attribute__((ext_vector_type(8))) short short8;
typedef __attribute__((ext_vector_type(4))) float floatx4;

#define TINV 14.2857142857142857f               // 1/0.07
#define TL2  20.60992915555662f                  // TINV * log2(e)
#define LN2  0.6931471805599453f
#define SQS  4.539816022451927f                  // sqrt(TL2): dot(fb,fb) = TL2*dot(f,f)
#define NROWS 8192
#define NDIM 128
#define NCH 16
#define NITS 8                                   // 8 x 64 cols = 512-col chunk
#define NBLOCKS 1024

__device__ __forceinline__ float fexp2(float x) {
#if __has_builtin(__builtin_amdgcn_exp2f)
    return __builtin_amdgcn_exp2f(x);
#else
    return __expf(x * LN2);
#endif
}

// fp32 -> bf16 (pre-scaled by sqrt(TL2)), written TRANSPOSED into fbT (coalesced).
// Also zeroes out[0] and the 18-word counter/accumulator block in workspace.
__global__ void convert_kernel(const float* __restrict__ in, unsigned short* __restrict__ fbT,
                               float* __restrict__ outz, unsigned int* __restrict__ zws) {
    const int i = blockIdx.x * 256 + threadIdx.x;   // 512 blocks -> 131072 = 16 kc x 8192 rows
    const int kc = i >> 13;
    const int row = i & 8191;
    const float4* p = (const float4*)(in + (size_t)row * NDIM + kc * 8);
    const float4 a = p[0], b = p[1];
    union { short8 s; __hip_bfloat162 h[4]; } t;
    t.h[0] = __float22bfloat162_rn(float2{a.x * SQS, a.y * SQS});
    t.h[1] = __float22bfloat162_rn(float2{a.z * SQS, a.w * SQS});
    t.h[2] = __float22bfloat162_rn(float2{b.x * SQS, b.y * SQS});
    t.h[3] = __float22bfloat162_rn(float2{b.z * SQS, b.w * SQS});
    ((short8*)fbT)[(size_t)kc * NROWS + row] = t.s;
    if (i < 18) zws[i] = 0u;                      // ctrs[16], gctr, nacc
    if (i == 0) outz[0] = 0.0f;
}

// grid 1024, 512-thread blocks: rb = blockIdx&63 (128 rows), q = blockIdx>>6 (512-col chunk).
// Round-4 body (proven 42.8us, VGPR 32, no spill) with:
//  - 64-col tiles: 8 barriers/block instead of 16 (2 col-pairs per iter, pair loop
//    NOT unrolled so its 8 ds_reads are not hoisted — the round-5 spill mechanism).
//  - final_k fused via per-rowgroup completion counters (round-7-validated
//    release/acquire protocol): 64th block of each 512-row group computes that
//    group's class term; 1024th block overall adds the noise term.
__global__ __launch_bounds__(512, 4) void supcon_main(
    const unsigned short* __restrict__ fbT,
    const int* __restrict__ labels,
    float* __restrict__ sM, float* __restrict__ sS, float* __restrict__ sP,
    unsigned int* __restrict__ ctrs,      // [16] rowgroup counters, [16]=gctr, [17]=nacc
    float* __restrict__ out)
{
    __shared__ __align__(16) short stage[2][16 * 64 * 8];   // [buf][kc][col] 16B units, 16KB each
    __shared__ float nredW[8];
    __shared__ int lab3[512];
    __shared__ int hist3[16];
    __shared__ float red3[512];
    __shared__ int amLast, amNoise;

    unsigned int* gctr = ctrs + 16;
    float* nacc = (float*)(ctrs + 17);

    const int rb = blockIdx.x & 63;
    const int q  = blockIdx.x >> 6;
    const int rg = rb >> 2;                       // rowgroup 0..15 (512 rows each)
    const int rowBase = rb << 7;
    const int colBase = q << 9;
    const int tid = threadIdx.x;
    const int w = __builtin_amdgcn_readfirstlane(tid >> 6);   // wave id 0..7 -> SGPR
    const int lane = tid & 63;
    const int l15 = lane & 15;
    const int l4  = lane >> 4;

    const short8* fb8 = (const short8*)fbT;

// issue staging for 64-col tile IT into buffer BUF: 2 instrs/wave, each 1KB = 1 kc-row x 64 cols
#define ISSUE(IT, BUF)                                                                   \
    {                                                                                    \
        unsigned short* sbase = (unsigned short*)&stage[BUF][0];                         \
        _Pragma("unroll")                                                                \
        for (int j = 0; j < 2; ++j) {                                                    \
            const int kc = (w << 1) + j;                                                 \
            const unsigned short* src = fbT +                                            \
                ((size_t)kc * NROWS + colBase + ((IT) << 6) + lane) * 8;                 \
            __builtin_amdgcn_global_load_lds(                                            \
                (const __attribute__((address_space(1))) unsigned int*)src,              \
                (__attribute__((address_space(3))) unsigned int*)(sbase + kc * 512),     \
                16, 0, 0);                                                               \
        }                                                                                \
    }

    ISSUE(0, 0)

    // A fragments: wave owns 16 rows (one rowset); from fbT (coalesced 256B segs)
    const int rw = rowBase + w * 16;                 // SGPR
    const int brow = rw >> 4;
    const int lrow = labels[brow];                    // uniform addr -> s_load
    short8 afrag[4];
    #pragma unroll
    for (int t = 0; t < 4; ++t)
        afrag[t] = fb8[(size_t)(t * 4 + l4) * NROWS + rw + l15];

    // scalar class-match mask over the 32 col-16 tiles of this chunk
    const int cb16 = colBase >> 4;
    unsigned pms = 0u;
    #pragma unroll
    for (int c = 0; c < 32; ++c)
        if (labels[cb16 + c] == lrow) pms |= (1u << c);

    float tm[4], su[4], ps[4];
    #pragma unroll
    for (int r = 0; r < 4; ++r) { tm[r] = -1e30f; su[r] = 0.0f; ps[r] = 0.0f; }
    float noise_acc = 0.0f;

    for (int it = 0; it < NITS; ++it) {
        __syncthreads();                 // drains my tile-it loads (vmcnt 0) + barrier
        if (it + 1 < NITS) ISSUE(it + 1, (it + 1) & 1)

        const short8* stv = (const short8*)stage[it & 1];

        #pragma clang loop unroll(disable)          // keep ds_reads inside: no hoist-spill
        for (int cp = 0; cp < 2; ++cp) {
            floatx4 vacc[2];
            #pragma unroll
            for (int c = 0; c < 2; ++c) {
                floatx4 acc = {0.0f, 0.0f, 0.0f, 0.0f};
                #pragma unroll
                for (int t = 0; t < 4; ++t) {
                    short8 bfrag = stv[(t * 4 + l4) * 64 + (cp << 5) + (c << 4) + l15];
                    acc = __builtin_amdgcn_mfma_f32_16x16x32_bf16(afrag[t], bfrag, acc, 0, 0, 0);
                }
                vacc[c] = acc;
            }

            const int pairIdx = (it << 1) + cp;     // 0..15
            const int base16 = cb16 + (pairIdx << 1);
            const int nt = brow - base16;          // same-batch tile index if in [0,2) — scalar
            const bool anyn = ((unsigned)nt) < 2u; // wave-uniform scalar
            int posm = (int)((pms >> (pairIdx << 1)) & 3u);
            if (anyn) posm &= ~(1 << nt);          // drop same-batch tile from positives
            #pragma unroll
            for (int r = 0; r < 4; ++r) {
                const float v0 = vacc[0][r], v1 = vacc[1][r];
                if (!anyn) {
                    const float lmax = fmaxf(v0, v1);
                    const float tmr = tm[r];
                    if (__any(lmax > tmr)) {
                        const float tnm = fmaxf(tmr, lmax);
                        su[r] = fmaf(su[r], fexp2(tmr - tnm),
                                     fexp2(v0 - tnm) + fexp2(v1 - tnm));
                        tm[r] = tnm;
                    } else {   // steady state: no rescale
                        su[r] += fexp2(v0 - tmr) + fexp2(v1 - tmr);
                    }
                } else {       // one of the two 16-tiles is same-batch (invalid + noise)
                    const float vv = nt ? v0 : v1;   // the valid tile's value
                    const float vn = nt ? v1 : v0;   // the same-batch tile's value
                    const float tmr = tm[r];
                    const float tnm = fmaxf(tmr, vv);
                    su[r] = fmaf(su[r], fexp2(tmr - tnm), fexp2(vv - tnm));
                    tm[r] = tnm;
                    const int rl = (l4 << 2) + r;
                    if ((rl >> 3) == (l15 >> 3) && rl != l15) noise_acc += vn;
                }
                if (posm & 1) ps[r] += v0;
                if (posm & 2) ps[r] += v1;
            }
        }
    }
#undef ISSUE

    // combine the 16 lane-partials per row via shuffles (l15 groups hold one row)
    #pragma unroll
    for (int r = 0; r < 4; ++r) {
        float tmv = tm[r], suv = su[r], psv = ps[r];
        #pragma unroll
        for (int off = 1; off < 16; off <<= 1) {
            float om = __shfl_xor(tmv, off);
            float os = __shfl_xor(suv, off);
            float op = __shfl_xor(psv, off);
            float nm = fmaxf(tmv, om);
            suv = suv * fexp2(tmv - nm) + os * fexp2(om - nm);
            tmv = nm; psv += op;
        }
        if (l15 == 0) {
            int row = rw + (l4 << 2) + r;
            sM[row * NCH + q] = tmv;
            sS[row * NCH + q] = suv;
            sP[row * NCH + q] = psv;
        }
    }

    float na = noise_acc;
    #pragma unroll
    for (int off = 32; off >= 1; off >>= 1) na += __shfl_xor(na, off);
    if (lane == 0) nredW[w] = na;
    __syncthreads();   // drains every thread's sM/sS/sP stores (vmcnt 0) + nredW visible

    // ---- completion protocol (round-7-validated release/acquire) ----
    if (tid == 0) {
        float s = 0.0f;
        #pragma unroll
        for (int j = 0; j < 8; ++j) s += nredW[j];
        atomicAdd(nacc, s);                       // device-scope (m20)
        __threadfence();                          // release: wbl2 before counter bumps
        const unsigned o1 = atomicAdd(&ctrs[rg], 1u);
        amLast = (o1 == 63u);                     // all 64 blocks of this rowgroup done
        const unsigned o2 = atomicAdd(gctr, 1u);
        amNoise = (o2 == NBLOCKS - 1u);           // all blocks done -> nacc complete
    }
    __syncthreads();

    if (amLast) {                                 // block-uniform
        __threadfence();                          // acquire: inv caches before reading sM/sS/sP
        if (tid < 16) hist3[tid] = 0;
        lab3[tid] = labels[tid];
        __syncthreads();
        atomicAdd(&hist3[lab3[tid] & 15], 1);
        __syncthreads();

        const int row = (rg << 9) + tid;          // 512 rows, one per thread
        float mq[NCH], sq[NCH], pq[NCH];
        const float4* M4 = (const float4*)(sM + (size_t)row * NCH);
        const float4* S4 = (const float4*)(sS + (size_t)row * NCH);
        const float4* P4 = (const float4*)(sP + (size_t)row * NCH);
        #pragma unroll
        for (int j = 0; j < 4; ++j) {
            float4 a = M4[j]; mq[4*j] = a.x; mq[4*j+1] = a.y; mq[4*j+2] = a.z; mq[4*j+3] = a.w;
            float4 b = S4[j]; sq[4*j] = b.x; sq[4*j+1] = b.y; sq[4*j+2] = b.z; sq[4*j+3] = b.w;
            float4 c = P4[j]; pq[4*j] = c.x; pq[4*j+1] = c.y; pq[4*j+2] = c.z; pq[4*j+3] = c.w;
        }
        float gm = -1e30f;
        #pragma unroll
        for (int qq = 0; qq < NCH; ++qq) gm = fmaxf(gm, mq[qq]);
        float gs = 0.0f, gp = 0.0f;
        #pragma unroll
        for (int qq = 0; qq < NCH; ++qq) { gs += sq[qq] * fexp2(mq[qq] - gm); gp += pq[qq]; }
        const float P = 16.0f * (float)(hist3[lab3[row >> 4] & 15] - 1);
        // log2-domain (pre-scaled features): term = LN2*(P*(gm+log2 gs) - possum)/(P+eps)
        red3[tid] = LN2 * (P * (gm + __log2f(gs)) - gp) / (P + 1e-8f);
        __syncthreads();
        #pragma unroll
        for (int off = 256; off > 0; off >>= 1) {
            if (tid < off) red3[tid] += red3[tid + off];
            __syncthreads();
        }
        if (tid == 0) atomicAdd(out, red3[0] * (1.0f / (8192.0f * 3.0f)));
    }

    if (amNoise && tid == 0) {                    // last block overall: noise term
        __threadfence();
        const float nz = __hip_atomic_load(nacc, __ATOMIC_RELAXED, __HIP_MEMORY_SCOPE_AGENT);
        atomicAdd(out, nz * (-LN2 / (57344.0f * 0.07f * 3.0f)));
    }
}

extern "C" void kernel_launch(void* const* d_in, const int* in_sizes, int n_in,
                              void* d_out, int out_size, void* d_ws, size_t ws_size,
                              hipStream_t stream) {
    const float* feat  = (const float*)d_in[0];
    const int* labels  = (const int*)d_in[1];
    float* out = (float*)d_out;

    unsigned short* fbT = (unsigned short*)d_ws;                   // 2 MB bf16 transposed
    float* wsf  = (float*)((char*)d_ws + (size_t)NROWS * NDIM * 2);
    float* sM   = wsf;                     // 8192*16
    float* sS   = wsf + 131072;
    float* sP   = wsf + 262144;
    unsigned int* ctrs = (unsigned int*)(wsf + 393216);   // [16] rowgroup, [16] gctr, [17] nacc

    hipLaunchKernelGGL(convert_kernel, dim3(512), dim3(256), 0, stream, feat, fbT, out, ctrs);
    hipLaunchKernelGGL(supcon_main, dim3(NBLOCKS), dim3(512), 0, stream,
                       fbT, labels, sM, sS, sP, ctrs, out);
}